// Round 1
// baseline (84.444 us; speedup 1.0000x reference)
//
#include <hip/hip_runtime.h>
#include <hip/hip_cooperative_groups.h>
#include <math.h>

namespace cg = cooperative_groups;

#define N_NODES 21
#define NODE_FEAT 128
#define N_ACTIONS 256

// ws float layout:
//   [0, 448)     v (441 used, 7 pad)
//   [448, 960)   acc1 (512)
//   [960, 1472)  acc2 (512)
//   [1472, 1728) acc3 (256)
#define WS_V    0
#define WS_ACC1 448
#define WS_ACC2 960
#define WS_ACC3 1472

__device__ __forceinline__ float agent_load(const float* p) {
    return __hip_atomic_load(p, __ATOMIC_RELAXED, __HIP_MEMORY_SCOPE_AGENT);
}

// One cooperative kernel replaces the previous 5-kernel chain.
// 64 blocks x 256 threads. Stage boundaries are grid.sync() instead of
// kernel launches. FC weights are prefetched into registers before the
// first sync so their load latency hides under block 0's GCN stage.
__global__ __launch_bounds__(256, 1) void fused_kernel(
    const float* __restrict__ state,      // [B,21,128], only batch 0 used
    const int*   __restrict__ edge_index, // [2,128]
    const float* __restrict__ W1,         // [128,21]
    const float* __restrict__ b1,         // [21]
    const float* __restrict__ W2,         // [21,21]
    const float* __restrict__ b2,         // [21]
    const float* __restrict__ Wf1,        // [441,512]
    const float* __restrict__ bf1,        // [512]
    const float* __restrict__ Wf2,        // [512,512]
    const float* __restrict__ bf2,        // [512]
    const float* __restrict__ Wf3,        // [512,256]
    const float* __restrict__ bf3,        // [256]
    float* __restrict__ ws,
    float* __restrict__ out)
{
    const int b = blockIdx.x;
    const int t = threadIdx.x;
    cg::grid_group grid = cg::this_grid();

    // ---------------- register prefetch (overlaps GCN stage) ----------------
    const int r1 = b * 7;   // FC1 rows, blocks 0..62 (63*7 = 441)
    const int r2 = b * 8;   // FC2/FC3 rows, blocks 0..63 (64*8 = 512)

    float wf1a[7], wf1b[7];
    if (b < 63) {
        #pragma unroll
        for (int r = 0; r < 7; ++r) {
            const float* row = Wf1 + (size_t)(r1 + r) * 512;
            wf1a[r] = row[t];
            wf1b[r] = row[t + 256];
        }
    }
    float wf2a[8], wf2b[8], bf1v[8];
    #pragma unroll
    for (int r = 0; r < 8; ++r) {
        const float* row = Wf2 + (size_t)(r2 + r) * 512;
        wf2a[r] = row[t];
        wf2b[r] = row[t + 256];
        bf1v[r] = bf1[r2 + r];
    }
    float wf3v[8], bf2v[8];
    #pragma unroll
    for (int r = 0; r < 8; ++r) {
        wf3v[r] = Wf3[(size_t)(r2 + r) * 256 + t];
        bf2v[r] = bf2[r2 + r];
    }
    const float bf3v = bf3[t];

    // ---------------- stage 0: GCN (block 0), acc zeroing (block 1) --------
    if (b == 0) {
        __shared__ float sA[441];
        __shared__ float sX[N_NODES * NODE_FEAT];   // 2688
        __shared__ float sW1[NODE_FEAT * 21];       // 2688
        __shared__ float sW2[441];
        __shared__ float sh[441];
        __shared__ float sg[441];
        __shared__ float sdinv[N_NODES];

        for (int i = t; i < 441; i += 256) sA[i] = 0.0f;
        __syncthreads();

        if (t < 128) {
            int r = edge_index[t];         // edge_index[0][t]
            int c = edge_index[128 + t];   // edge_index[1][t]
            atomicAdd(&sA[r * 21 + c], 1.0f);
        }
        __syncthreads();

        if (t < 21) sA[t * 21 + t] += 1.0f;
        __syncthreads();

        if (t < 21) {
            float d = 0.0f;
            for (int i = 0; i < 21; ++i) d += sA[i * 21 + t];
            sdinv[t] = 1.0f / sqrtf(d);
        }
        __syncthreads();

        for (int i = t; i < 441; i += 256) {
            int ii = i / 21, jj = i % 21;
            sA[i] = sdinv[ii] * sA[i] * sdinv[jj];
        }
        for (int i = t; i < N_NODES * NODE_FEAT; i += 256) sX[i] = state[i];
        for (int i = t; i < NODE_FEAT * 21; i += 256)      sW1[i] = W1[i];
        for (int i = t; i < 441; i += 256)                 sW2[i] = W2[i];
        __syncthreads();

        // h1[n,k] = sum_f X[n,f] * W1[f,k]
        for (int i = t; i < 441; i += 256) {
            int n = i / 21, k = i % 21;
            float s = 0.0f;
            for (int f = 0; f < NODE_FEAT; ++f) s += sX[n * NODE_FEAT + f] * sW1[f * 21 + k];
            sh[i] = s;
        }
        __syncthreads();

        // g1[i,k] = b1[k] + sum_j A[i,j] * h1[j,k]
        for (int i = t; i < 441; i += 256) {
            int ii = i / 21, k = i % 21;
            float s = b1[k];
            for (int j = 0; j < 21; ++j) s += sA[ii * 21 + j] * sh[j * 21 + k];
            sg[i] = s;
        }
        __syncthreads();

        // h2[n,k] = sum_f g1[n,f] * W2[f,k]
        for (int i = t; i < 441; i += 256) {
            int n = i / 21, k = i % 21;
            float s = 0.0f;
            for (int f = 0; f < 21; ++f) s += sg[n * 21 + f] * sW2[f * 21 + k];
            sh[i] = s;
        }
        __syncthreads();

        // v[i*21+k] = b2[k] + sum_j A[i,j] * h2[j,k]
        for (int i = t; i < 441; i += 256) {
            int ii = i / 21, k = i % 21;
            float s = b2[k];
            for (int j = 0; j < 21; ++j) s += sA[ii * 21 + j] * sh[j * 21 + k];
            ws[WS_V + i] = s;
        }
    } else if (b == 1) {
        // zero acc1(512) + acc2(512) + acc3(256) = 1280 floats
        for (int i = t; i < 1280; i += 256) ws[WS_ACC1 + i] = 0.0f;
    }

    __threadfence();
    grid.sync();

    // ---------------- FC1: v[441] @ Wf1 -> acc1 (split-K atomics) ----------
    if (b < 63) {
        float s0 = 0.0f, s1 = 0.0f;
        #pragma unroll
        for (int r = 0; r < 7; ++r) {
            float vv = agent_load(&ws[WS_V + r1 + r]);
            s0 += vv * wf1a[r];
            s1 += vv * wf1b[r];
        }
        atomicAdd(&ws[WS_ACC1 + t],       s0);
        atomicAdd(&ws[WS_ACC1 + t + 256], s1);
    }

    __threadfence();
    grid.sync();

    // ---------------- FC2: relu(acc1+bf1) @ Wf2 -> acc2 ----------
    {
        float s0 = 0.0f, s1 = 0.0f;
        #pragma unroll
        for (int r = 0; r < 8; ++r) {
            float a = agent_load(&ws[WS_ACC1 + r2 + r]) + bf1v[r];
            a = a > 0.0f ? a : 0.0f;
            s0 += a * wf2a[r];
            s1 += a * wf2b[r];
        }
        atomicAdd(&ws[WS_ACC2 + t],       s0);
        atomicAdd(&ws[WS_ACC2 + t + 256], s1);
    }

    __threadfence();
    grid.sync();

    // ---------------- FC3: relu(acc2+bf2) @ Wf3 -> acc3 ----------
    {
        float s = 0.0f;
        #pragma unroll
        for (int r = 0; r < 8; ++r) {
            float a = agent_load(&ws[WS_ACC2 + r2 + r]) + bf2v[r];
            a = a > 0.0f ? a : 0.0f;
            s += a * wf3v[r];
        }
        atomicAdd(&ws[WS_ACC3 + t], s);
    }

    __threadfence();
    grid.sync();

    // ---------------- finalize: out = relu(acc3 + bf3) ----------
    if (b == 0) {
        float a = agent_load(&ws[WS_ACC3 + t]) + bf3v;
        out[t] = a > 0.0f ? a : 0.0f;
    }
}

extern "C" void kernel_launch(void* const* d_in, const int* in_sizes, int n_in,
                              void* d_out, int out_size, void* d_ws, size_t ws_size,
                              hipStream_t stream)
{
    const float* state      = (const float*)d_in[0];
    const int*   edge_index = (const int*)  d_in[1];
    const float* W1  = (const float*)d_in[2];
    const float* b1  = (const float*)d_in[3];
    const float* W2  = (const float*)d_in[4];
    const float* b2  = (const float*)d_in[5];
    const float* Wf1 = (const float*)d_in[6];
    const float* bf1 = (const float*)d_in[7];
    const float* Wf2 = (const float*)d_in[8];
    const float* bf2 = (const float*)d_in[9];
    const float* Wf3 = (const float*)d_in[10];
    const float* bf3 = (const float*)d_in[11];

    float* ws  = (float*)d_ws;
    float* out = (float*)d_out;

    void* args[] = {
        (void*)&state, (void*)&edge_index,
        (void*)&W1, (void*)&b1, (void*)&W2, (void*)&b2,
        (void*)&Wf1, (void*)&bf1, (void*)&Wf2, (void*)&bf2,
        (void*)&Wf3, (void*)&bf3,
        (void*)&ws, (void*)&out
    };
    hipLaunchCooperativeKernel((const void*)fused_kernel, dim3(64), dim3(256),
                               args, 0, stream);
}

// Round 2
// 36.772 us; speedup vs baseline: 2.2964x; 2.2964x over previous
//
#include <hip/hip_runtime.h>
#include <math.h>

#define N_NODES 21
#define NODE_FEAT 128
#define N_ACTIONS 256

// ws float layout (write-before-read every iteration; poison-safe):
//   [0, 512)    acc1
//   [512, 1024) acc2
#define WS_ACC1 0
#define WS_ACC2 512

// Grid barrier state. __device__ globals are zero-initialized at module load
// and the sense-reversing barrier restores (ctr=0) after each use, so state
// is consistent across hipGraph replays and rocprof counter replays.
__device__ unsigned g_bar_ctr = 0;
__device__ unsigned g_bar_sense = 0;

__device__ __forceinline__ float agent_load(const float* p) {
    return __hip_atomic_load(p, __ATOMIC_RELAXED, __HIP_MEMORY_SCOPE_AGENT);
}
__device__ __forceinline__ void agent_store(float* p, float v) {
    __hip_atomic_store(p, v, __ATOMIC_RELAXED, __HIP_MEMORY_SCOPE_AGENT);
}

// Sense-reversing grid barrier. Requires all blocks co-resident
// (64 blocks of 256 threads on 256 CUs: trivially satisfied).
__device__ __forceinline__ void grid_barrier(unsigned nblocks) {
    __syncthreads();
    if (threadIdx.x == 0) {
        __threadfence();   // release prior writes to agent scope
        unsigned s = __hip_atomic_load(&g_bar_sense, __ATOMIC_RELAXED,
                                       __HIP_MEMORY_SCOPE_AGENT);
        unsigned prev = __hip_atomic_fetch_add(&g_bar_ctr, 1u, __ATOMIC_ACQ_REL,
                                               __HIP_MEMORY_SCOPE_AGENT);
        if (prev == nblocks - 1u) {
            // last arriver: reset counter, then flip sense with release
            __hip_atomic_store(&g_bar_ctr, 0u, __ATOMIC_RELAXED,
                               __HIP_MEMORY_SCOPE_AGENT);
            __hip_atomic_store(&g_bar_sense, s ^ 1u, __ATOMIC_RELEASE,
                               __HIP_MEMORY_SCOPE_AGENT);
        } else {
            while (__hip_atomic_load(&g_bar_sense, __ATOMIC_ACQUIRE,
                                     __HIP_MEMORY_SCOPE_AGENT) == s) {
                __builtin_amdgcn_s_sleep(1);
            }
        }
    }
    __syncthreads();
    __threadfence();       // invalidate L1 so post-barrier reads are fresh
}

// Single regular launch, 64 blocks x 256 threads.
// Stage 0: GCN computed REDUNDANTLY in every block (tiny: ~23KB in, 56K MACs)
//          -> v lives in LDS of every block, no barrier needed before FC1.
// Stage 1: FC1 full-K per column slice: block b -> acc1[8b..8b+8).  barrier.
// Stage 2: FC2 full-K per column slice: block b -> acc2[8b..8b+8).  barrier.
// Stage 3: FC3 + finalize: block b -> out[4b..4b+4).
// No atomics on accumulators, no zero-init pass, finalize fused into FC3.
__global__ __launch_bounds__(256) void fused_kernel(
    const float* __restrict__ state,      // [B,21,128], only batch 0 used
    const int*   __restrict__ edge_index, // [2,128]
    const float* __restrict__ W1,         // [128,21]
    const float* __restrict__ b1,         // [21]
    const float* __restrict__ W2,         // [21,21]
    const float* __restrict__ b2,         // [21]
    const float* __restrict__ Wf1,        // [441,512]
    const float* __restrict__ bf1,        // [512]
    const float* __restrict__ Wf2,        // [512,512]
    const float* __restrict__ bf2,        // [512]
    const float* __restrict__ Wf3,        // [512,256]
    const float* __restrict__ bf3,        // [256]
    float* __restrict__ ws,
    float* __restrict__ out)
{
    const int b = blockIdx.x;
    const int t = threadIdx.x;

    __shared__ float sA[441];
    __shared__ float sX[N_NODES * NODE_FEAT];   // 2688
    __shared__ float sW1[NODE_FEAT * 21];       // 2688
    __shared__ float sW2[441];
    __shared__ float sh[441];
    __shared__ float sg[441];
    __shared__ float sv[441];
    __shared__ float sdinv[N_NODES];
    __shared__ float xs[512];

    // ---------------- GCN (every block, redundant) ----------------
    for (int i = t; i < 441; i += 256) sA[i] = 0.0f;
    __syncthreads();

    if (t < 128) {
        int r = edge_index[t];         // edge_index[0][t]
        int c = edge_index[128 + t];   // edge_index[1][t]
        atomicAdd(&sA[r * 21 + c], 1.0f);
    }
    __syncthreads();

    if (t < 21) sA[t * 21 + t] += 1.0f;
    __syncthreads();

    if (t < 21) {
        float d = 0.0f;
        for (int i = 0; i < 21; ++i) d += sA[i * 21 + t];
        sdinv[t] = 1.0f / sqrtf(d);
    }
    __syncthreads();

    for (int i = t; i < 441; i += 256) {
        int ii = i / 21, jj = i % 21;
        sA[i] = sdinv[ii] * sA[i] * sdinv[jj];
    }
    for (int i = t; i < N_NODES * NODE_FEAT; i += 256) sX[i] = state[i];
    for (int i = t; i < NODE_FEAT * 21; i += 256)      sW1[i] = W1[i];
    for (int i = t; i < 441; i += 256)                 sW2[i] = W2[i];
    __syncthreads();

    // h1[n,k] = sum_f X[n,f] * W1[f,k]
    for (int i = t; i < 441; i += 256) {
        int n = i / 21, k = i % 21;
        float s = 0.0f;
        for (int f = 0; f < NODE_FEAT; ++f) s += sX[n * NODE_FEAT + f] * sW1[f * 21 + k];
        sh[i] = s;
    }
    __syncthreads();

    // g1[i,k] = b1[k] + sum_j A[i,j] * h1[j,k]
    for (int i = t; i < 441; i += 256) {
        int ii = i / 21, k = i % 21;
        float s = b1[k];
        for (int j = 0; j < 21; ++j) s += sA[ii * 21 + j] * sh[j * 21 + k];
        sg[i] = s;
    }
    __syncthreads();

    // h2[n,k] = sum_f g1[n,f] * W2[f,k]
    for (int i = t; i < 441; i += 256) {
        int n = i / 21, k = i % 21;
        float s = 0.0f;
        for (int f = 0; f < 21; ++f) s += sg[n * 21 + f] * sW2[f * 21 + k];
        sh[i] = s;
    }
    __syncthreads();

    // v[i*21+k] = b2[k] + sum_j A[i,j] * h2[j,k]
    for (int i = t; i < 441; i += 256) {
        int ii = i / 21, k = i % 21;
        float s = b2[k];
        for (int j = 0; j < 21; ++j) s += sA[ii * 21 + j] * sh[j * 21 + k];
        sv[i] = s;
    }
    __syncthreads();

    // ---------------- FC1: block b owns acc1[8b .. 8b+8) ----------------
    // 8 columns x 32 lanes; full K=441 per column, shuffle-reduce.
    const int cl = t >> 5;        // 0..7 column within slice
    const int ln = t & 31;        // 0..31 lane within column group
    {
        const int c = b * 8 + cl;
        const float* __restrict__ wcol = Wf1 + c;
        float s = 0.0f;
        #pragma unroll
        for (int i = 0; i < 14; ++i) {
            int r = ln + 32 * i;
            if (r < 441) s += sv[r] * wcol[(size_t)r * 512];
        }
        #pragma unroll
        for (int m = 16; m; m >>= 1) s += __shfl_xor(s, m, 64);
        if (ln == 0) agent_store(&ws[WS_ACC1 + c], s);
    }

    grid_barrier(64);

    // ---------------- FC2: block b owns acc2[8b .. 8b+8) ----------------
    for (int i = t; i < 512; i += 256)
        xs[i] = fmaxf(agent_load(&ws[WS_ACC1 + i]) + bf1[i], 0.0f);
    __syncthreads();
    {
        const int c = b * 8 + cl;
        const float* __restrict__ wcol = Wf2 + c;
        float s = 0.0f;
        #pragma unroll
        for (int i = 0; i < 16; ++i) {
            int r = ln + 32 * i;
            s += xs[r] * wcol[(size_t)r * 512];
        }
        #pragma unroll
        for (int m = 16; m; m >>= 1) s += __shfl_xor(s, m, 64);
        if (ln == 0) agent_store(&ws[WS_ACC2 + c], s);
    }

    grid_barrier(64);

    // ---------------- FC3 + finalize: block b owns out[4b .. 4b+4) -------
    for (int i = t; i < 512; i += 256)
        xs[i] = fmaxf(agent_load(&ws[WS_ACC2 + i]) + bf2[i], 0.0f);
    __syncthreads();
    {
        const int c3 = t >> 6;    // 0..3 column within slice
        const int l6 = t & 63;    // lane within wave
        const int c = b * 4 + c3;
        const float* __restrict__ wcol = Wf3 + c;
        float s = 0.0f;
        #pragma unroll
        for (int i = 0; i < 8; ++i) {
            int r = l6 + 64 * i;
            s += xs[r] * wcol[(size_t)r * 256];
        }
        #pragma unroll
        for (int m = 32; m; m >>= 1) s += __shfl_xor(s, m, 64);
        if (l6 == 0) out[c] = fmaxf(s + bf3[c], 0.0f);
    }
}

extern "C" void kernel_launch(void* const* d_in, const int* in_sizes, int n_in,
                              void* d_out, int out_size, void* d_ws, size_t ws_size,
                              hipStream_t stream)
{
    const float* state      = (const float*)d_in[0];
    const int*   edge_index = (const int*)  d_in[1];
    const float* W1  = (const float*)d_in[2];
    const float* b1  = (const float*)d_in[3];
    const float* W2  = (const float*)d_in[4];
    const float* b2  = (const float*)d_in[5];
    const float* Wf1 = (const float*)d_in[6];
    const float* bf1 = (const float*)d_in[7];
    const float* Wf2 = (const float*)d_in[8];
    const float* bf2 = (const float*)d_in[9];
    const float* Wf3 = (const float*)d_in[10];
    const float* bf3 = (const float*)d_in[11];

    float* ws  = (float*)d_ws;
    float* out = (float*)d_out;

    fused_kernel<<<64, 256, 0, stream>>>(state, edge_index, W1, b1, W2, b2,
                                         Wf1, bf1, Wf2, bf2, Wf3, bf3, ws, out);
}

// Round 3
// 32.017 us; speedup vs baseline: 2.6375x; 1.1485x over previous
//
#include <hip/hip_runtime.h>
#include <math.h>

#define N_NODES 21
#define NODE_FEAT 128
#define N_ACTIONS 256
#define APAD 28          // padded row stride for 21-wide tiles (16B aligned, spreads bank starts)
#define W1PAD 132        // padded row stride for 128-wide tiles

// ws float layout (write-before-read every iteration; poison-safe):
#define WS_ACC1 0
#define WS_ACC2 512

// Epoch-flag grid barrier state. Each block writes ONLY its own flag (no RMW).
// Flags are monotonic; each launch reads its own flag as the epoch base, so
// state is consistent across hipGraph replays / rocprof counter replays.
__device__ unsigned g_flags[64];

__device__ __forceinline__ float agent_load(const float* p) {
    return __hip_atomic_load(p, __ATOMIC_RELAXED, __HIP_MEMORY_SCOPE_AGENT);
}
__device__ __forceinline__ void agent_store(float* p, float v) {
    __hip_atomic_store(p, v, __ATOMIC_RELAXED, __HIP_MEMORY_SCOPE_AGENT);
}

// Contention-free barrier: block stores flag[b] = base+phase (plain store, no RMW);
// lanes 0..63 poll the 64 flags with relaxed loads until all reach base+phase.
__device__ __forceinline__ void grid_barrier(int blk, unsigned base, unsigned phase) {
    __syncthreads();
    if (threadIdx.x < 64) {
        const unsigned target = base + phase;
        if (threadIdx.x == 0) {
            __threadfence();   // release prior writes to agent scope
            __hip_atomic_store(&g_flags[blk], target, __ATOMIC_RELAXED,
                               __HIP_MEMORY_SCOPE_AGENT);
        }
        for (;;) {
            unsigned f = __hip_atomic_load(&g_flags[threadIdx.x], __ATOMIC_RELAXED,
                                           __HIP_MEMORY_SCOPE_AGENT);
            if ((int)(f - target) >= 0) break;
            __builtin_amdgcn_s_sleep(1);
        }
    }
    __syncthreads();
    __threadfence();           // acquire: post-barrier reads see released data
}

// Single launch, 64 blocks x 256 threads.
// GCN computed redundantly per block (vectorized, conflict-padded LDS).
// FC1/FC2/FC3 column-sliced full-K per block (no atomics), weights preloaded
// into registers before the GCN so their latency hides completely.
__global__ __launch_bounds__(256) void fused_kernel(
    const float* __restrict__ state,      // [B,21,128], only batch 0 used
    const int*   __restrict__ edge_index, // [2,128]
    const float* __restrict__ W1,         // [128,21]
    const float* __restrict__ b1,         // [21]
    const float* __restrict__ W2,         // [21,21]
    const float* __restrict__ b2,         // [21]
    const float* __restrict__ Wf1,        // [441,512]
    const float* __restrict__ bf1,        // [512]
    const float* __restrict__ Wf2,        // [512,512]
    const float* __restrict__ bf2,        // [512]
    const float* __restrict__ Wf3,        // [512,256]
    const float* __restrict__ bf3,        // [256]
    float* __restrict__ ws,
    float* __restrict__ out)
{
    const int b = blockIdx.x;
    const int t = threadIdx.x;

    // ---------------- register prefetch (completes during GCN) -------------
    const int cl = t >> 5, ln = t & 31;     // FC1/FC2: 8 cols x 32 lanes
    const int c1 = b * 8 + cl;
    const int c3 = t >> 6, l6 = t & 63;     // FC3: 4 cols x 64 lanes
    const int c3g = b * 4 + c3;

    float wf1v[14];
    #pragma unroll
    for (int i = 0; i < 14; ++i) {
        int r = ln + 32 * i;
        wf1v[i] = (r < 441) ? Wf1[(size_t)r * 512 + c1] : 0.0f;
    }
    float wf2v[16];
    #pragma unroll
    for (int i = 0; i < 16; ++i) wf2v[i] = Wf2[(size_t)(ln + 32 * i) * 512 + c1];
    float wf3v[8];
    #pragma unroll
    for (int i = 0; i < 8; ++i) wf3v[i] = Wf3[(size_t)(l6 + 64 * i) * 256 + c3g];
    const float rbf1a = bf1[t], rbf1b = bf1[t + 256];
    const float rbf2a = bf2[t], rbf2b = bf2[t + 256];
    const float rbf3  = bf3[c3g];
    const unsigned bbase = __hip_atomic_load(&g_flags[b], __ATOMIC_RELAXED,
                                             __HIP_MEMORY_SCOPE_AGENT);

    // ---------------- LDS ----------------
    __shared__ float sA[21 * APAD];      // normalized adjacency, rows padded, pads 0
    __shared__ float sX[21 * W1PAD];     // X rows, stride 132
    __shared__ float sW1T[21 * W1PAD];   // W1^T [k][f], stride 132
    __shared__ float sW2T[21 * APAD];    // W2^T [k][f], pads 0
    __shared__ float sT[21 * APAD];      // transposed intermediate (h1T, then h2T)
    __shared__ float sG[21 * APAD];      // g1 row-major padded
    __shared__ float sv[448];            // v (441) + zero pad
    __shared__ float sdinv[21];
    __shared__ float sb1[21], sb2[21];
    __shared__ float xs[512];

    // zero padded tiles (pads must be 0 so float4 dots over 24 cols are exact)
    for (int i = t; i < 21 * APAD; i += 256) {
        sA[i] = 0.0f; sW2T[i] = 0.0f; sT[i] = 0.0f; sG[i] = 0.0f;
    }
    if (t < 7) sv[441 + t] = 0.0f;
    if (t < 21) { sb1[t] = b1[t]; sb2[t] = b2[t]; }
    __syncthreads();

    // ---------------- adjacency build + normalize ----------------
    if (t < 128) {
        int r = edge_index[t];
        int c = edge_index[128 + t];
        atomicAdd(&sA[r * APAD + c], 1.0f);
    }
    __syncthreads();
    if (t < 21) sA[t * APAD + t] += 1.0f;
    __syncthreads();
    if (t < 21) {
        float d = 0.0f;
        for (int i = 0; i < 21; ++i) d += sA[i * APAD + t];
        sdinv[t] = 1.0f / sqrtf(d);
    }
    __syncthreads();
    for (int i = t; i < 21 * APAD; i += 256) {
        int r = i / APAD, c = i - r * APAD;
        if (c < 21) sA[i] = sdinv[r] * sA[i] * sdinv[c];
    }

    // ---------------- stage X, W1^T, W2^T ----------------
    {
        const float4* src4 = (const float4*)state;      // batch 0, contiguous
        for (int i = t; i < 672; i += 256) {            // 21*128/4
            int n = i >> 5, fc = i & 31;
            ((float4*)&sX[n * W1PAD])[fc] = src4[i];
        }
    }
    for (int i = t; i < 2688; i += 256) {               // W1[f*21+k] -> sW1T[k][f]
        int f = i / 21, k = i - f * 21;
        sW1T[k * W1PAD + f] = W1[i];
    }
    for (int i = t; i < 441; i += 256) {                // W2[f*21+k] -> sW2T[k][f]
        int f = i / 21, k = i - f * 21;
        sW2T[k * APAD + f] = W2[i];
    }
    __syncthreads();

    // ---------------- h1 = X @ W1, stored transposed: sT[k][n] ----------------
    for (int i = t; i < 441; i += 256) {
        int n = i / 21, k = i - n * 21;
        const float4* x4 = (const float4*)&sX[n * W1PAD];
        const float4* w4 = (const float4*)&sW1T[k * W1PAD];
        float s = 0.0f;
        #pragma unroll
        for (int fc = 0; fc < 32; ++fc) {
            float4 a = x4[fc], w = w4[fc];
            s += a.x * w.x; s += a.y * w.y; s += a.z * w.z; s += a.w * w.w;
        }
        sT[k * APAD + n] = s;
    }
    __syncthreads();

    // ---------------- g1[i,k] = b1[k] + A[i,:] . h1T[k,:]  (row-major out) ----
    for (int i = t; i < 441; i += 256) {
        int r = i / 21, k = i - r * 21;
        const float4* a4 = (const float4*)&sA[r * APAD];
        const float4* h4 = (const float4*)&sT[k * APAD];
        float s = sb1[k];
        #pragma unroll
        for (int jc = 0; jc < 6; ++jc) {
            float4 a = a4[jc], h = h4[jc];
            s += a.x * h.x; s += a.y * h.y; s += a.z * h.z; s += a.w * h.w;
        }
        sG[r * APAD + k] = s;
    }
    __syncthreads();

    // ---------------- h2[n,k] = g1[n,:] . W2T[k,:], stored transposed ---------
    for (int i = t; i < 441; i += 256) {
        int n = i / 21, k = i - n * 21;
        const float4* g4 = (const float4*)&sG[n * APAD];
        const float4* w4 = (const float4*)&sW2T[k * APAD];
        float s = 0.0f;
        #pragma unroll
        for (int jc = 0; jc < 6; ++jc) {
            float4 g = g4[jc], w = w4[jc];
            s += g.x * w.x; s += g.y * w.y; s += g.z * w.z; s += g.w * w.w;
        }
        sT[k * APAD + n] = s;   // overwrite h1T with h2T (g1 already consumed... next sync guards)
    }
    __syncthreads();

    // ---------------- v[i*21+k] = b2[k] + A[i,:] . h2T[k,:] ----------------
    for (int i = t; i < 441; i += 256) {
        int r = i / 21, k = i - r * 21;
        const float4* a4 = (const float4*)&sA[r * APAD];
        const float4* h4 = (const float4*)&sT[k * APAD];
        float s = sb2[k];
        #pragma unroll
        for (int jc = 0; jc < 6; ++jc) {
            float4 a = a4[jc], h = h4[jc];
            s += a.x * h.x; s += a.y * h.y; s += a.z * h.z; s += a.w * h.w;
        }
        sv[i] = s;
    }
    __syncthreads();

    // ---------------- FC1: block owns acc1[8b .. 8b+8) ----------------
    {
        float s = 0.0f;
        #pragma unroll
        for (int i = 0; i < 14; ++i) s += sv[ln + 32 * i] * wf1v[i];  // pads zero
        #pragma unroll
        for (int m = 16; m; m >>= 1) s += __shfl_xor(s, m, 64);
        if (ln == 0) agent_store(&ws[WS_ACC1 + c1], s);
    }

    grid_barrier(b, bbase, 1);

    // ---------------- FC2: block owns acc2[8b .. 8b+8) ----------------
    xs[t]       = fmaxf(agent_load(&ws[WS_ACC1 + t])       + rbf1a, 0.0f);
    xs[t + 256] = fmaxf(agent_load(&ws[WS_ACC1 + t + 256]) + rbf1b, 0.0f);
    __syncthreads();
    {
        float s = 0.0f;
        #pragma unroll
        for (int i = 0; i < 16; ++i) s += xs[ln + 32 * i] * wf2v[i];
        #pragma unroll
        for (int m = 16; m; m >>= 1) s += __shfl_xor(s, m, 64);
        if (ln == 0) agent_store(&ws[WS_ACC2 + c1], s);
    }

    grid_barrier(b, bbase, 2);

    // ---------------- FC3 + finalize: block owns out[4b .. 4b+4) ----------
    xs[t]       = fmaxf(agent_load(&ws[WS_ACC2 + t])       + rbf2a, 0.0f);
    xs[t + 256] = fmaxf(agent_load(&ws[WS_ACC2 + t + 256]) + rbf2b, 0.0f);
    __syncthreads();
    {
        float s = 0.0f;
        #pragma unroll
        for (int i = 0; i < 8; ++i) s += xs[l6 + 64 * i] * wf3v[i];
        #pragma unroll
        for (int m = 32; m; m >>= 1) s += __shfl_xor(s, m, 64);
        if (l6 == 0) out[c3g] = fmaxf(s + rbf3, 0.0f);
    }
}

extern "C" void kernel_launch(void* const* d_in, const int* in_sizes, int n_in,
                              void* d_out, int out_size, void* d_ws, size_t ws_size,
                              hipStream_t stream)
{
    const float* state      = (const float*)d_in[0];
    const int*   edge_index = (const int*)  d_in[1];
    const float* W1  = (const float*)d_in[2];
    const float* b1  = (const float*)d_in[3];
    const float* W2  = (const float*)d_in[4];
    const float* b2  = (const float*)d_in[5];
    const float* Wf1 = (const float*)d_in[6];
    const float* bf1 = (const float*)d_in[7];
    const float* Wf2 = (const float*)d_in[8];
    const float* bf2 = (const float*)d_in[9];
    const float* Wf3 = (const float*)d_in[10];
    const float* bf3 = (const float*)d_in[11];

    float* ws  = (float*)d_ws;
    float* out = (float*)d_out;

    fused_kernel<<<64, 256, 0, stream>>>(state, edge_index, W1, b1, W2, b2,
                                         Wf1, bf1, Wf2, bf2, Wf3, bf3, ws, out);
}

// Round 4
// 23.988 us; speedup vs baseline: 3.5203x; 1.3347x over previous
//
#include <hip/hip_runtime.h>
#include <math.h>

#define N_NODES 21
#define NODE_FEAT 128
#define N_ACTIONS 256
#define APAD 28          // padded row stride for 21-wide tiles (16B aligned, spreads bank starts)
#define W1PAD 132        // padded row stride for 128-wide tiles

// ws float layout (write-before-read every iteration; poison-safe):
#define WS_ACC1 0
#define WS_ACC2 512

// Epoch-flag grid barrier state. Each block writes ONLY its own flag (no RMW).
// Flags are monotonic; each launch reads its own flag as the epoch base, so
// state is consistent across hipGraph replays / rocprof counter replays.
__device__ unsigned g_flags[64];

// All cross-block data moves through agent-scope RELAXED atomics. The backend
// emits these as sc0/sc1 cache-BYPASSING loads/stores served at the coherence
// point (Infinity Cache), so no L2 writeback/invalidate fences are needed
// anywhere. Ordering "data stores done before flag store" is provided by
// __syncthreads(): the compiler drains vmcnt(0) before s_barrier, and store-ack
// from the coherence point == global visibility (this is how LLVM lowers a
// release, minus the catastrophic buffer_wbl2/buffer_inv this avoids).
__device__ __forceinline__ float agent_load(const float* p) {
    return __hip_atomic_load(p, __ATOMIC_RELAXED, __HIP_MEMORY_SCOPE_AGENT);
}
__device__ __forceinline__ void agent_store(float* p, float v) {
    __hip_atomic_store(p, v, __ATOMIC_RELAXED, __HIP_MEMORY_SCOPE_AGENT);
}

// Fence-free contention-free barrier: block stores flag[b] (plain bypassing
// store, no RMW); lanes 0..63 poll the 64 flags with relaxed bypassing loads.
__device__ __forceinline__ void grid_barrier(int blk, unsigned base, unsigned phase) {
    __syncthreads();                        // drains this block's data stores (vmcnt 0)
    if (threadIdx.x < 64) {
        const unsigned target = base + phase;
        if (threadIdx.x == 0) {
            __hip_atomic_store(&g_flags[blk], target, __ATOMIC_RELAXED,
                               __HIP_MEMORY_SCOPE_AGENT);
        }
        for (;;) {
            unsigned f = __hip_atomic_load(&g_flags[threadIdx.x], __ATOMIC_RELAXED,
                                           __HIP_MEMORY_SCOPE_AGENT);
            if ((int)(f - target) >= 0) break;
            __builtin_amdgcn_s_sleep(1);
        }
    }
    __syncthreads();                        // compiler fence; post-barrier reads bypass caches
}

// Single launch, 64 blocks x 256 threads.
// GCN computed redundantly per block (vectorized, conflict-padded LDS).
// FC1/FC2/FC3 column-sliced full-K per block (no atomics), weights preloaded
// into registers before the GCN so their latency hides completely.
__global__ __launch_bounds__(256) void fused_kernel(
    const float* __restrict__ state,      // [B,21,128], only batch 0 used
    const int*   __restrict__ edge_index, // [2,128]
    const float* __restrict__ W1,         // [128,21]
    const float* __restrict__ b1,         // [21]
    const float* __restrict__ W2,         // [21,21]
    const float* __restrict__ b2,         // [21]
    const float* __restrict__ Wf1,        // [441,512]
    const float* __restrict__ bf1,        // [512]
    const float* __restrict__ Wf2,        // [512,512]
    const float* __restrict__ bf2,        // [512]
    const float* __restrict__ Wf3,        // [512,256]
    const float* __restrict__ bf3,        // [256]
    float* __restrict__ ws,
    float* __restrict__ out)
{
    const int b = blockIdx.x;
    const int t = threadIdx.x;

    // ---------------- register prefetch (completes during GCN) -------------
    const int cl = t >> 5, ln = t & 31;     // FC1/FC2: 8 cols x 32 lanes
    const int c1 = b * 8 + cl;
    const int c3 = t >> 6, l6 = t & 63;     // FC3: 4 cols x 64 lanes
    const int c3g = b * 4 + c3;

    float wf1v[14];
    #pragma unroll
    for (int i = 0; i < 14; ++i) {
        int r = ln + 32 * i;
        wf1v[i] = (r < 441) ? Wf1[(size_t)r * 512 + c1] : 0.0f;
    }
    float wf2v[16];
    #pragma unroll
    for (int i = 0; i < 16; ++i) wf2v[i] = Wf2[(size_t)(ln + 32 * i) * 512 + c1];
    float wf3v[8];
    #pragma unroll
    for (int i = 0; i < 8; ++i) wf3v[i] = Wf3[(size_t)(l6 + 64 * i) * 256 + c3g];
    const float rbf1a = bf1[t], rbf1b = bf1[t + 256];
    const float rbf2a = bf2[t], rbf2b = bf2[t + 256];
    const float rbf3  = bf3[c3g];
    const unsigned bbase = __hip_atomic_load(&g_flags[b], __ATOMIC_RELAXED,
                                             __HIP_MEMORY_SCOPE_AGENT);

    // ---------------- LDS ----------------
    __shared__ float sA[21 * APAD];      // normalized adjacency, rows padded, pads 0
    __shared__ float sX[21 * W1PAD];     // X rows, stride 132
    __shared__ float sW1T[21 * W1PAD];   // W1^T [k][f], stride 132
    __shared__ float sW2T[21 * APAD];    // W2^T [k][f], pads 0
    __shared__ float sT[21 * APAD];      // transposed intermediate (h1T, then h2T)
    __shared__ float sG[21 * APAD];      // g1 row-major padded
    __shared__ float sv[448];            // v (441) + zero pad
    __shared__ float sdinv[21];
    __shared__ float sb1[21], sb2[21];
    __shared__ float xs[512];

    // zero padded tiles (pads must be 0 so float4 dots over 24 cols are exact)
    for (int i = t; i < 21 * APAD; i += 256) {
        sA[i] = 0.0f; sW2T[i] = 0.0f; sT[i] = 0.0f; sG[i] = 0.0f;
    }
    if (t < 7) sv[441 + t] = 0.0f;
    if (t < 21) { sb1[t] = b1[t]; sb2[t] = b2[t]; }
    __syncthreads();

    // ---------------- adjacency build + normalize ----------------
    if (t < 128) {
        int r = edge_index[t];
        int c = edge_index[128 + t];
        atomicAdd(&sA[r * APAD + c], 1.0f);
    }
    __syncthreads();
    if (t < 21) sA[t * APAD + t] += 1.0f;
    __syncthreads();
    if (t < 21) {
        float d = 0.0f;
        for (int i = 0; i < 21; ++i) d += sA[i * APAD + t];
        sdinv[t] = 1.0f / sqrtf(d);
    }
    __syncthreads();
    for (int i = t; i < 21 * APAD; i += 256) {
        int r = i / APAD, c = i - r * APAD;
        if (c < 21) sA[i] = sdinv[r] * sA[i] * sdinv[c];
    }

    // ---------------- stage X, W1^T, W2^T ----------------
    {
        const float4* src4 = (const float4*)state;      // batch 0, contiguous
        for (int i = t; i < 672; i += 256) {            // 21*128/4
            int n = i >> 5, fc = i & 31;
            ((float4*)&sX[n * W1PAD])[fc] = src4[i];
        }
    }
    for (int i = t; i < 2688; i += 256) {               // W1[f*21+k] -> sW1T[k][f]
        int f = i / 21, k = i - f * 21;
        sW1T[k * W1PAD + f] = W1[i];
    }
    for (int i = t; i < 441; i += 256) {                // W2[f*21+k] -> sW2T[k][f]
        int f = i / 21, k = i - f * 21;
        sW2T[k * APAD + f] = W2[i];
    }
    __syncthreads();

    // ---------------- h1 = X @ W1, stored transposed: sT[k][n] ----------------
    for (int i = t; i < 441; i += 256) {
        int n = i / 21, k = i - n * 21;
        const float4* x4 = (const float4*)&sX[n * W1PAD];
        const float4* w4 = (const float4*)&sW1T[k * W1PAD];
        float s = 0.0f;
        #pragma unroll
        for (int fc = 0; fc < 32; ++fc) {
            float4 a = x4[fc], w = w4[fc];
            s += a.x * w.x; s += a.y * w.y; s += a.z * w.z; s += a.w * w.w;
        }
        sT[k * APAD + n] = s;
    }
    __syncthreads();

    // ---------------- g1[i,k] = b1[k] + A[i,:] . h1T[k,:]  (row-major out) ----
    for (int i = t; i < 441; i += 256) {
        int r = i / 21, k = i - r * 21;
        const float4* a4 = (const float4*)&sA[r * APAD];
        const float4* h4 = (const float4*)&sT[k * APAD];
        float s = sb1[k];
        #pragma unroll
        for (int jc = 0; jc < 6; ++jc) {
            float4 a = a4[jc], h = h4[jc];
            s += a.x * h.x; s += a.y * h.y; s += a.z * h.z; s += a.w * h.w;
        }
        sG[r * APAD + k] = s;
    }
    __syncthreads();

    // ---------------- h2[n,k] = g1[n,:] . W2T[k,:], stored transposed ---------
    for (int i = t; i < 441; i += 256) {
        int n = i / 21, k = i - n * 21;
        const float4* g4 = (const float4*)&sG[n * APAD];
        const float4* w4 = (const float4*)&sW2T[k * APAD];
        float s = 0.0f;
        #pragma unroll
        for (int jc = 0; jc < 6; ++jc) {
            float4 g = g4[jc], w = w4[jc];
            s += g.x * w.x; s += g.y * w.y; s += g.z * w.z; s += g.w * w.w;
        }
        sT[k * APAD + n] = s;
    }
    __syncthreads();

    // ---------------- v[i*21+k] = b2[k] + A[i,:] . h2T[k,:] ----------------
    for (int i = t; i < 441; i += 256) {
        int r = i / 21, k = i - r * 21;
        const float4* a4 = (const float4*)&sA[r * APAD];
        const float4* h4 = (const float4*)&sT[k * APAD];
        float s = sb2[k];
        #pragma unroll
        for (int jc = 0; jc < 6; ++jc) {
            float4 a = a4[jc], h = h4[jc];
            s += a.x * h.x; s += a.y * h.y; s += a.z * h.z; s += a.w * h.w;
        }
        sv[i] = s;
    }
    __syncthreads();

    // ---------------- FC1: block owns acc1[8b .. 8b+8) ----------------
    {
        float s = 0.0f;
        #pragma unroll
        for (int i = 0; i < 14; ++i) s += sv[ln + 32 * i] * wf1v[i];  // pads zero
        #pragma unroll
        for (int m = 16; m; m >>= 1) s += __shfl_xor(s, m, 64);
        if (ln == 0) agent_store(&ws[WS_ACC1 + c1], s);
    }

    grid_barrier(b, bbase, 1);

    // ---------------- FC2: block owns acc2[8b .. 8b+8) ----------------
    xs[t]       = fmaxf(agent_load(&ws[WS_ACC1 + t])       + rbf1a, 0.0f);
    xs[t + 256] = fmaxf(agent_load(&ws[WS_ACC1 + t + 256]) + rbf1b, 0.0f);
    __syncthreads();
    {
        float s = 0.0f;
        #pragma unroll
        for (int i = 0; i < 16; ++i) s += xs[ln + 32 * i] * wf2v[i];
        #pragma unroll
        for (int m = 16; m; m >>= 1) s += __shfl_xor(s, m, 64);
        if (ln == 0) agent_store(&ws[WS_ACC2 + c1], s);
    }

    grid_barrier(b, bbase, 2);

    // ---------------- FC3 + finalize: block owns out[4b .. 4b+4) ----------
    xs[t]       = fmaxf(agent_load(&ws[WS_ACC2 + t])       + rbf2a, 0.0f);
    xs[t + 256] = fmaxf(agent_load(&ws[WS_ACC2 + t + 256]) + rbf2b, 0.0f);
    __syncthreads();
    {
        float s = 0.0f;
        #pragma unroll
        for (int i = 0; i < 8; ++i) s += xs[l6 + 64 * i] * wf3v[i];
        #pragma unroll
        for (int m = 32; m; m >>= 1) s += __shfl_xor(s, m, 64);
        if (l6 == 0) out[c3g] = fmaxf(s + rbf3, 0.0f);
    }
}

extern "C" void kernel_launch(void* const* d_in, const int* in_sizes, int n_in,
                              void* d_out, int out_size, void* d_ws, size_t ws_size,
                              hipStream_t stream)
{
    const float* state      = (const float*)d_in[0];
    const int*   edge_index = (const int*)  d_in[1];
    const float* W1  = (const float*)d_in[2];
    const float* b1  = (const float*)d_in[3];
    const float* W2  = (const float*)d_in[4];
    const float* b2  = (const float*)d_in[5];
    const float* Wf1 = (const float*)d_in[6];
    const float* bf1 = (const float*)d_in[7];
    const float* Wf2 = (const float*)d_in[8];
    const float* bf2 = (const float*)d_in[9];
    const float* Wf3 = (const float*)d_in[10];
    const float* bf3 = (const float*)d_in[11];

    float* ws  = (float*)d_ws;
    float* out = (float*)d_out;

    fused_kernel<<<64, 256, 0, stream>>>(state, edge_index, W1, b1, W2, b2,
                                         Wf1, bf1, Wf2, bf2, Wf3, bf3, ws, out);
}

// Round 5
// 22.293 us; speedup vs baseline: 3.7878x; 1.0760x over previous
//
#include <hip/hip_runtime.h>
#include <math.h>

#define N_NODES 21
#define NODE_FEAT 128
#define N_ACTIONS 256
#define APAD 28          // padded row stride for 21-wide tiles (16B aligned, spreads bank starts)
#define W1PAD 132        // padded row stride for 128-wide tiles

// ws float layout (write-before-read every iteration; poison-safe):
#define WS_ACC1 0
#define WS_ACC2 512

// Hierarchical epoch barrier state (monotonic; consistent across graph replays).
// Arrival flags are 64B-strided so each block's arrival store hits its own
// cacheline. Only block 0 polls arrivals; everyone else polls the single g_go
// word with ONE lane per block (~100x less coherence-point traffic than
// all-blocks x all-lanes polling).
__device__ unsigned g_arrive[64 * 16];   // slot b*16; slot 0 unused (leader)
__device__ unsigned g_go;

// All cross-block data moves through agent-scope RELAXED atomics (sc0/sc1
// cache-bypassing ops served at the coherence point) -> no L2 wb/inv fences
// needed. "Data stores drained before flag store" is provided by
// __syncthreads() (compiler emits s_waitcnt vmcnt(0) before s_barrier).
__device__ __forceinline__ float agent_load(const float* p) {
    return __hip_atomic_load(p, __ATOMIC_RELAXED, __HIP_MEMORY_SCOPE_AGENT);
}
__device__ __forceinline__ void agent_store(float* p, float v) {
    __hip_atomic_store(p, v, __ATOMIC_RELAXED, __HIP_MEMORY_SCOPE_AGENT);
}
__device__ __forceinline__ unsigned flag_load(const unsigned* p) {
    return __hip_atomic_load(p, __ATOMIC_RELAXED, __HIP_MEMORY_SCOPE_AGENT);
}
__device__ __forceinline__ void flag_store(unsigned* p, unsigned v) {
    __hip_atomic_store(p, v, __ATOMIC_RELAXED, __HIP_MEMORY_SCOPE_AGENT);
}

__device__ __forceinline__ void grid_barrier(int blk, unsigned base, unsigned phase) {
    const unsigned target = base + phase;
    __syncthreads();                          // drain this block's data stores
    if (blk == 0) {
        // leader: lanes 1..63 poll their block's arrival slot; loop exits
        // when ALL lanes' conditions hold (exec-mask wave-AND for free).
        if (threadIdx.x > 0 && threadIdx.x < 64) {
            for (;;) {
                unsigned f = flag_load(&g_arrive[threadIdx.x * 16]);
                if ((int)(f - target) >= 0) break;
                __builtin_amdgcn_s_sleep(1);
            }
        }
        if (threadIdx.x == 0) flag_store(&g_go, target);
    } else {
        if (threadIdx.x == 0) {
            flag_store(&g_arrive[blk * 16], target);
            for (;;) {
                unsigned f = flag_load(&g_go);
                if ((int)(f - target) >= 0) break;
                __builtin_amdgcn_s_sleep(1);
            }
        }
    }
    __syncthreads();                          // broadcast exit; compiler fence
}

// Single launch, 64 blocks x 256 threads.
// GCN computed redundantly per block (vectorized, conflict-padded LDS).
// FC1/FC2/FC3 column-sliced full-K per block (no atomics), weights preloaded
// into registers before the GCN so their latency hides completely.
__global__ __launch_bounds__(256) void fused_kernel(
    const float* __restrict__ state,      // [B,21,128], only batch 0 used
    const int*   __restrict__ edge_index, // [2,128]
    const float* __restrict__ W1,         // [128,21]
    const float* __restrict__ b1,         // [21]
    const float* __restrict__ W2,         // [21,21]
    const float* __restrict__ b2,         // [21]
    const float* __restrict__ Wf1,        // [441,512]
    const float* __restrict__ bf1,        // [512]
    const float* __restrict__ Wf2,        // [512,512]
    const float* __restrict__ bf2,        // [512]
    const float* __restrict__ Wf3,        // [512,256]
    const float* __restrict__ bf3,        // [256]
    float* __restrict__ ws,
    float* __restrict__ out)
{
    const int b = blockIdx.x;
    const int t = threadIdx.x;

    // ---------------- register prefetch (completes during GCN) -------------
    const int cl = t >> 5, ln = t & 31;     // FC1/FC2: 8 cols x 32 lanes
    const int c1 = b * 8 + cl;
    const int c3 = t >> 6, l6 = t & 63;     // FC3: 4 cols x 64 lanes
    const int c3g = b * 4 + c3;

    float wf1v[14];
    #pragma unroll
    for (int i = 0; i < 14; ++i) {
        int r = ln + 32 * i;
        wf1v[i] = (r < 441) ? Wf1[(size_t)r * 512 + c1] : 0.0f;
    }
    float wf2v[16];
    #pragma unroll
    for (int i = 0; i < 16; ++i) wf2v[i] = Wf2[(size_t)(ln + 32 * i) * 512 + c1];
    float wf3v[8];
    #pragma unroll
    for (int i = 0; i < 8; ++i) wf3v[i] = Wf3[(size_t)(l6 + 64 * i) * 256 + c3g];
    const float rbf1a = bf1[t], rbf1b = bf1[t + 256];
    const float rbf2a = bf2[t], rbf2b = bf2[t + 256];
    const float rbf3  = bf3[c3g];
    const unsigned bbase = flag_load(&g_go);   // consistent epoch base

    // ---------------- LDS ----------------
    __shared__ float sA[21 * APAD];      // normalized adjacency, rows padded, pads 0
    __shared__ float sX[21 * W1PAD];     // X rows, stride 132
    __shared__ float sW1T[21 * W1PAD];   // W1^T [k][f], stride 132
    __shared__ float sW2T[21 * APAD];    // W2^T [k][f], pads 0
    __shared__ float sT[21 * APAD];      // transposed intermediate (h1T, then h2T)
    __shared__ float sG[21 * APAD];      // g1 row-major padded
    __shared__ float sv[448];            // v (441) + zero pad
    __shared__ float sdinv[21];
    __shared__ float sb1[21], sb2[21];
    __shared__ float xs[512];

    // zero padded tiles (pads must be 0 so float4 dots over 24 cols are exact)
    for (int i = t; i < 21 * APAD; i += 256) {
        sA[i] = 0.0f; sW2T[i] = 0.0f; sT[i] = 0.0f; sG[i] = 0.0f;
    }
    if (t < 7) sv[441 + t] = 0.0f;
    if (t < 21) { sb1[t] = b1[t]; sb2[t] = b2[t]; }
    __syncthreads();

    // ---------------- adjacency build + normalize ----------------
    if (t < 128) {
        int r = edge_index[t];
        int c = edge_index[128 + t];
        atomicAdd(&sA[r * APAD + c], 1.0f);
    }
    __syncthreads();
    if (t < 21) sA[t * APAD + t] += 1.0f;
    __syncthreads();
    if (t < 21) {
        float d = 0.0f;
        for (int i = 0; i < 21; ++i) d += sA[i * APAD + t];
        sdinv[t] = 1.0f / sqrtf(d);
    }
    __syncthreads();
    for (int i = t; i < 21 * APAD; i += 256) {
        int r = i / APAD, c = i - r * APAD;
        if (c < 21) sA[i] = sdinv[r] * sA[i] * sdinv[c];
    }

    // ---------------- stage X, W1^T, W2^T ----------------
    {
        const float4* src4 = (const float4*)state;      // batch 0, contiguous
        for (int i = t; i < 672; i += 256) {            // 21*128/4
            int n = i >> 5, fc = i & 31;
            ((float4*)&sX[n * W1PAD])[fc] = src4[i];
        }
    }
    for (int i = t; i < 2688; i += 256) {               // W1[f*21+k] -> sW1T[k][f]
        int f = i / 21, k = i - f * 21;
        sW1T[k * W1PAD + f] = W1[i];
    }
    for (int i = t; i < 441; i += 256) {                // W2[f*21+k] -> sW2T[k][f]
        int f = i / 21, k = i - f * 21;
        sW2T[k * APAD + f] = W2[i];
    }
    __syncthreads();

    // ---------------- h1 = X @ W1, stored transposed: sT[k][n] ----------------
    for (int i = t; i < 441; i += 256) {
        int n = i / 21, k = i - n * 21;
        const float4* x4 = (const float4*)&sX[n * W1PAD];
        const float4* w4 = (const float4*)&sW1T[k * W1PAD];
        float s = 0.0f;
        #pragma unroll
        for (int fc = 0; fc < 32; ++fc) {
            float4 a = x4[fc], w = w4[fc];
            s += a.x * w.x; s += a.y * w.y; s += a.z * w.z; s += a.w * w.w;
        }
        sT[k * APAD + n] = s;
    }
    __syncthreads();

    // ---------------- g1[i,k] = b1[k] + A[i,:] . h1T[k,:]  (row-major out) ----
    for (int i = t; i < 441; i += 256) {
        int r = i / 21, k = i - r * 21;
        const float4* a4 = (const float4*)&sA[r * APAD];
        const float4* h4 = (const float4*)&sT[k * APAD];
        float s = sb1[k];
        #pragma unroll
        for (int jc = 0; jc < 6; ++jc) {
            float4 a = a4[jc], h = h4[jc];
            s += a.x * h.x; s += a.y * h.y; s += a.z * h.z; s += a.w * h.w;
        }
        sG[r * APAD + k] = s;
    }
    __syncthreads();

    // ---------------- h2[n,k] = g1[n,:] . W2T[k,:], stored transposed ---------
    for (int i = t; i < 441; i += 256) {
        int n = i / 21, k = i - n * 21;
        const float4* g4 = (const float4*)&sG[n * APAD];
        const float4* w4 = (const float4*)&sW2T[k * APAD];
        float s = 0.0f;
        #pragma unroll
        for (int jc = 0; jc < 6; ++jc) {
            float4 g = g4[jc], w = w4[jc];
            s += g.x * w.x; s += g.y * w.y; s += g.z * w.z; s += g.w * w.w;
        }
        sT[k * APAD + n] = s;
    }
    __syncthreads();

    // ---------------- v[i*21+k] = b2[k] + A[i,:] . h2T[k,:] ----------------
    for (int i = t; i < 441; i += 256) {
        int r = i / 21, k = i - r * 21;
        const float4* a4 = (const float4*)&sA[r * APAD];
        const float4* h4 = (const float4*)&sT[k * APAD];
        float s = sb2[k];
        #pragma unroll
        for (int jc = 0; jc < 6; ++jc) {
            float4 a = a4[jc], h = h4[jc];
            s += a.x * h.x; s += a.y * h.y; s += a.z * h.z; s += a.w * h.w;
        }
        sv[i] = s;
    }
    __syncthreads();

    // ---------------- FC1: block owns acc1[8b .. 8b+8) ----------------
    {
        float s = 0.0f;
        #pragma unroll
        for (int i = 0; i < 14; ++i) s += sv[ln + 32 * i] * wf1v[i];  // pads zero
        #pragma unroll
        for (int m = 16; m; m >>= 1) s += __shfl_xor(s, m, 64);
        if (ln == 0) agent_store(&ws[WS_ACC1 + c1], s);
    }

    grid_barrier(b, bbase, 1);

    // ---------------- FC2: block owns acc2[8b .. 8b+8) ----------------
    xs[t]       = fmaxf(agent_load(&ws[WS_ACC1 + t])       + rbf1a, 0.0f);
    xs[t + 256] = fmaxf(agent_load(&ws[WS_ACC1 + t + 256]) + rbf1b, 0.0f);
    __syncthreads();
    {
        float s = 0.0f;
        #pragma unroll
        for (int i = 0; i < 16; ++i) s += xs[ln + 32 * i] * wf2v[i];
        #pragma unroll
        for (int m = 16; m; m >>= 1) s += __shfl_xor(s, m, 64);
        if (ln == 0) agent_store(&ws[WS_ACC2 + c1], s);
    }

    grid_barrier(b, bbase, 2);

    // ---------------- FC3 + finalize: block owns out[4b .. 4b+4) ----------
    xs[t]       = fmaxf(agent_load(&ws[WS_ACC2 + t])       + rbf2a, 0.0f);
    xs[t + 256] = fmaxf(agent_load(&ws[WS_ACC2 + t + 256]) + rbf2b, 0.0f);
    __syncthreads();
    {
        float s = 0.0f;
        #pragma unroll
        for (int i = 0; i < 8; ++i) s += xs[l6 + 64 * i] * wf3v[i];
        #pragma unroll
        for (int m = 32; m; m >>= 1) s += __shfl_xor(s, m, 64);
        if (l6 == 0) out[c3g] = fmaxf(s + rbf3, 0.0f);
    }
}

extern "C" void kernel_launch(void* const* d_in, const int* in_sizes, int n_in,
                              void* d_out, int out_size, void* d_ws, size_t ws_size,
                              hipStream_t stream)
{
    const float* state      = (const float*)d_in[0];
    const int*   edge_index = (const int*)  d_in[1];
    const float* W1  = (const float*)d_in[2];
    const float* b1  = (const float*)d_in[3];
    const float* W2  = (const float*)d_in[4];
    const float* b2  = (const float*)d_in[5];
    const float* Wf1 = (const float*)d_in[6];
    const float* bf1 = (const float*)d_in[7];
    const float* Wf2 = (const float*)d_in[8];
    const float* bf2 = (const float*)d_in[9];
    const float* Wf3 = (const float*)d_in[10];
    const float* bf3 = (const float*)d_in[11];

    float* ws  = (float*)d_ws;
    float* out = (float*)d_out;

    fused_kernel<<<64, 256, 0, stream>>>(state, edge_index, W1, b1, W2, b2,
                                         Wf1, bf1, Wf2, bf2, Wf3, bf3, ws, out);
}

// Round 6
// 19.374 us; speedup vs baseline: 4.3587x; 1.1507x over previous
//
#include <hip/hip_runtime.h>
#include <math.h>

#define N_NODES 21
#define NODE_FEAT 128
#define N_ACTIONS 256
#define APAD 28          // padded row stride for 21-wide tiles
#define W1PAD 132        // padded row stride for 128-wide tiles

// ws float layout (write-before-read every iteration; poison-safe):
#define WS_ACC1 0
#define WS_ACC2 512

// Hierarchical epoch barrier state (monotonic; consistent across graph replays).
__device__ unsigned g_arrive[64 * 16];   // 64B-strided arrival slots
__device__ unsigned g_go;

// Agent-scope relaxed atomics: sc0/sc1 cache-bypassing ops served at the
// coherence point -> no L2 wb/inv fences needed anywhere.
__device__ __forceinline__ float agent_load(const float* p) {
    return __hip_atomic_load(p, __ATOMIC_RELAXED, __HIP_MEMORY_SCOPE_AGENT);
}
__device__ __forceinline__ void agent_store(float* p, float v) {
    __hip_atomic_store(p, v, __ATOMIC_RELAXED, __HIP_MEMORY_SCOPE_AGENT);
}
__device__ __forceinline__ unsigned flag_load(const unsigned* p) {
    return __hip_atomic_load(p, __ATOMIC_RELAXED, __HIP_MEMORY_SCOPE_AGENT);
}
__device__ __forceinline__ void flag_store(unsigned* p, unsigned v) {
    __hip_atomic_store(p, v, __ATOMIC_RELAXED, __HIP_MEMORY_SCOPE_AGENT);
}

// Block barrier that waits ONLY on LDS ops (lgkmcnt), NOT vmcnt: global
// prefetch loads stay in flight across it. __syncthreads() would drain
// vmcnt(0) and serialize the scattered FC-weight prefetch onto the GCN
// critical path (documented hipcc s_barrier lowering).
__device__ __forceinline__ void lds_barrier() {
    asm volatile("s_waitcnt lgkmcnt(0)\n\ts_barrier" ::: "memory");
}

// Hierarchical grid barrier (entry __syncthreads provides vmcnt(0) drain of
// the data stores; leader block 0 collects arrivals, publishes g_go).
__device__ __forceinline__ void grid_barrier(int blk, unsigned base, unsigned phase) {
    const unsigned target = base + phase;
    __syncthreads();                          // drain this block's data stores
    if (blk == 0) {
        if (threadIdx.x > 0 && threadIdx.x < 64) {
            for (;;) {
                unsigned f = flag_load(&g_arrive[threadIdx.x * 16]);
                if ((int)(f - target) >= 0) break;
                __builtin_amdgcn_s_sleep(1);
            }
        }
        if (threadIdx.x == 0) flag_store(&g_go, target);
    } else {
        if (threadIdx.x == 0) {
            flag_store(&g_arrive[blk * 16], target);
            for (;;) {
                unsigned f = flag_load(&g_go);
                if ((int)(f - target) >= 0) break;
                __builtin_amdgcn_s_sleep(1);
            }
        }
    }
    __syncthreads();
}

// Single launch, 64 blocks x 512 threads (8 waves -> 2 waves/SIMD).
__global__ __launch_bounds__(512) void fused_kernel(
    const float* __restrict__ state,      // [B,21,128], only batch 0 used
    const int*   __restrict__ edge_index, // [2,128]
    const float* __restrict__ W1,         // [128,21]
    const float* __restrict__ b1,         // [21]
    const float* __restrict__ W2,         // [21,21]
    const float* __restrict__ b2,         // [21]
    const float* __restrict__ Wf1,        // [441,512]
    const float* __restrict__ bf1,        // [512]
    const float* __restrict__ Wf2,        // [512,512]
    const float* __restrict__ bf2,        // [512]
    const float* __restrict__ Wf3,        // [512,256]
    const float* __restrict__ bf3,        // [256]
    float* __restrict__ ws,
    float* __restrict__ out)
{
    const int b = blockIdx.x;
    const int t = threadIdx.x;
    const int l6 = t & 63;          // lane in wave
    const int w  = t >> 6;          // wave 0..7
    const int c1 = b * 8 + w;       // FC1/FC2 column owned by this wave
    const int c3 = w & 3;           // FC3 column (4 cols x 2 waves)
    const int half = w >> 2;        // FC3 K-half
    const int c3g = b * 4 + c3;

    const unsigned bbase = flag_load(&g_go);   // epoch base

    // ---------------- LDS ----------------
    __shared__ float sA[21 * APAD];
    __shared__ float sX[21 * W1PAD];
    __shared__ float sW1T[21 * W1PAD];
    __shared__ float sW2T[21 * APAD];
    __shared__ float sT[21 * APAD];
    __shared__ float sG[21 * APAD];
    __shared__ float sv[448];
    __shared__ float sdinv[21];
    __shared__ float sb1[21], sb2[21];
    __shared__ float xs[512];
    __shared__ float pf[8];

    // ---- phase 0: zero pads; stage X/W1T (issues HBM loads earliest) ----
    for (int i = t; i < 21 * APAD; i += 512) {
        sA[i] = 0.0f; sW2T[i] = 0.0f; sT[i] = 0.0f; sG[i] = 0.0f;
    }
    if (t < 7) sv[441 + t] = 0.0f;
    if (t < 21) { sb1[t] = b1[t]; sb2[t] = b2[t]; }
    {
        const float4* src4 = (const float4*)state;      // batch 0
        for (int i = t; i < 672; i += 512) {            // 21*128/4
            int n = i >> 5, fc = i & 31;
            ((float4*)&sX[n * W1PAD])[fc] = src4[i];
        }
    }
    for (int i = t; i < 2688; i += 512) {               // W1 -> sW1T[k][f]
        int f = i / 21, k = i - f * 21;
        sW1T[k * W1PAD + f] = W1[i];
    }
    int er = 0, ec = 0;
    if (t < 128) { er = edge_index[t]; ec = edge_index[128 + t]; }

    // ---- FC weight prefetch: issued after staging loads; stays in flight
    // across all lds_barrier()s, consumed only at FC stages. ----
    float wf1v[7];
    #pragma unroll
    for (int i = 0; i < 7; ++i) {
        int r = l6 + 64 * i;
        wf1v[i] = (r < 441) ? Wf1[(size_t)r * 512 + c1] : 0.0f;
    }
    float wf2v[8];
    #pragma unroll
    for (int i = 0; i < 8; ++i) wf2v[i] = Wf2[(size_t)(l6 + 64 * i) * 512 + c1];
    float wf3v[4];
    #pragma unroll
    for (int i = 0; i < 4; ++i)
        wf3v[i] = Wf3[(size_t)(half * 256 + 64 * i + l6) * 256 + c3g];
    const float rbf1  = bf1[t];
    const float rbf2  = bf2[t];
    const float rbf3f = bf3[b * 4 + (t & 3)];

    lds_barrier();

    // ---- adjacency build ----
    if (t < 128) atomicAdd(&sA[er * APAD + ec], 1.0f);
    for (int i = t; i < 441; i += 512) {                // W2 -> sW2T[k][f]
        int f = i / 21, k = i - f * 21;
        sW2T[k * APAD + f] = W2[i];
    }
    lds_barrier();
    if (t < 21) sA[t * APAD + t] += 1.0f;
    lds_barrier();
    if (t < 21) {
        float d = 0.0f;
        for (int i = 0; i < 21; ++i) d += sA[i * APAD + t];
        sdinv[t] = 1.0f / sqrtf(d);
    }
    lds_barrier();
    for (int i = t; i < 21 * APAD; i += 512) {
        int r = i / APAD, c = i - r * APAD;
        if (c < 21) sA[i] = sdinv[r] * sA[i] * sdinv[c];
    }
    lds_barrier();

    // ---- h1 = X @ W1, stored transposed sT[k][n] ----
    if (t < 441) {
        int n = t / 21, k = t - n * 21;
        const float4* x4 = (const float4*)&sX[n * W1PAD];
        const float4* w4 = (const float4*)&sW1T[k * W1PAD];
        float s = 0.0f;
        #pragma unroll
        for (int fc = 0; fc < 32; ++fc) {
            float4 a = x4[fc], ww = w4[fc];
            s += a.x * ww.x; s += a.y * ww.y; s += a.z * ww.z; s += a.w * ww.w;
        }
        sT[k * APAD + n] = s;
    }
    lds_barrier();

    // ---- g1[i,k] = b1[k] + A[i,:] . h1T[k,:] ----
    if (t < 441) {
        int r = t / 21, k = t - r * 21;
        const float4* a4 = (const float4*)&sA[r * APAD];
        const float4* h4 = (const float4*)&sT[k * APAD];
        float s = sb1[k];
        #pragma unroll
        for (int jc = 0; jc < 6; ++jc) {
            float4 a = a4[jc], h = h4[jc];
            s += a.x * h.x; s += a.y * h.y; s += a.z * h.z; s += a.w * h.w;
        }
        sG[r * APAD + k] = s;
    }
    lds_barrier();

    // ---- h2[n,k] = g1[n,:] . W2T[k,:], stored transposed ----
    if (t < 441) {
        int n = t / 21, k = t - n * 21;
        const float4* g4 = (const float4*)&sG[n * APAD];
        const float4* w4 = (const float4*)&sW2T[k * APAD];
        float s = 0.0f;
        #pragma unroll
        for (int jc = 0; jc < 6; ++jc) {
            float4 g = g4[jc], ww = w4[jc];
            s += g.x * ww.x; s += g.y * ww.y; s += g.z * ww.z; s += g.w * ww.w;
        }
        sT[k * APAD + n] = s;
    }
    lds_barrier();

    // ---- v[i*21+k] = b2[k] + A[i,:] . h2T[k,:] ----
    if (t < 441) {
        int r = t / 21, k = t - r * 21;
        const float4* a4 = (const float4*)&sA[r * APAD];
        const float4* h4 = (const float4*)&sT[k * APAD];
        float s = sb2[k];
        #pragma unroll
        for (int jc = 0; jc < 6; ++jc) {
            float4 a = a4[jc], h = h4[jc];
            s += a.x * h.x; s += a.y * h.y; s += a.z * h.z; s += a.w * h.w;
        }
        sv[t] = s;
    }
    lds_barrier();

    // ---- FC1: wave w computes acc1[b*8+w] (full-wave reduce) ----
    {
        float s = 0.0f;
        #pragma unroll
        for (int i = 0; i < 7; ++i) s += sv[l6 + 64 * i] * wf1v[i];  // pads 0
        #pragma unroll
        for (int m = 32; m; m >>= 1) s += __shfl_xor(s, m, 64);
        if (l6 == 0) agent_store(&ws[WS_ACC1 + c1], s);
    }

    grid_barrier(b, bbase, 1);

    // ---- FC2: wave w computes acc2[b*8+w] ----
    xs[t] = fmaxf(agent_load(&ws[WS_ACC1 + t]) + rbf1, 0.0f);
    lds_barrier();
    {
        float s = 0.0f;
        #pragma unroll
        for (int i = 0; i < 8; ++i) s += xs[l6 + 64 * i] * wf2v[i];
        #pragma unroll
        for (int m = 32; m; m >>= 1) s += __shfl_xor(s, m, 64);
        if (l6 == 0) agent_store(&ws[WS_ACC2 + c1], s);
    }

    grid_barrier(b, bbase, 2);

    // ---- FC3 + finalize: 4 cols x 2 wave-halves, combine via pf[] ----
    xs[t] = fmaxf(agent_load(&ws[WS_ACC2 + t]) + rbf2, 0.0f);
    lds_barrier();
    {
        float s = 0.0f;
        #pragma unroll
        for (int i = 0; i < 4; ++i) s += xs[half * 256 + 64 * i + l6] * wf3v[i];
        #pragma unroll
        for (int m = 32; m; m >>= 1) s += __shfl_xor(s, m, 64);
        if (l6 == 0) pf[w] = s;
    }
    lds_barrier();
    if (t < 4) out[b * 4 + t] = fmaxf(pf[t] + pf[t + 4] + rbf3f, 0.0f);
}

extern "C" void kernel_launch(void* const* d_in, const int* in_sizes, int n_in,
                              void* d_out, int out_size, void* d_ws, size_t ws_size,
                              hipStream_t stream)
{
    const float* state      = (const float*)d_in[0];
    const int*   edge_index = (const int*)  d_in[1];
    const float* W1  = (const float*)d_in[2];
    const float* b1  = (const float*)d_in[3];
    const float* W2  = (const float*)d_in[4];
    const float* b2  = (const float*)d_in[5];
    const float* Wf1 = (const float*)d_in[6];
    const float* bf1 = (const float*)d_in[7];
    const float* Wf2 = (const float*)d_in[8];
    const float* bf2 = (const float*)d_in[9];
    const float* Wf3 = (const float*)d_in[10];
    const float* bf3 = (const float*)d_in[11];

    float* ws  = (float*)d_ws;
    float* out = (float*)d_out;

    fused_kernel<<<64, 512, 0, stream>>>(state, edge_index, W1, b1, W2, b2,
                                         Wf1, bf1, Wf2, bf2, Wf3, bf3, ws, out);
}

// Round 7
// 17.387 us; speedup vs baseline: 4.8567x; 1.1142x over previous
//
#include <hip/hip_runtime.h>
#include <math.h>

#define N_NODES 21
#define NODE_FEAT 128
#define N_ACTIONS 256
#define APAD 28          // padded row stride for 21-wide tiles
#define W1PAD 132        // padded row stride for 128-wide tiles

// ws float layout (acc zeroed by block 0 each launch; poison-safe):
#define WS_ACC1 0
#define WS_ACC2 512
#define WS_ACC3 1024

// Monotonic epoch sync state (zero-init at module load; replay-safe:
// every launch reads its own base first).
__device__ unsigned g_arrive[64 * 16];   // 64B-strided arrival slots
__device__ unsigned g_go;                // zero-ready(+1), bar1(+2), bar2(+3)
__device__ unsigned g_cnt;               // completion counter (finale trick)

// Agent-scope relaxed atomics: cache-bypassing ops served at the coherence
// point -> no L2 wb/inv fences needed anywhere.
__device__ __forceinline__ float agent_load(const float* p) {
    return __hip_atomic_load(p, __ATOMIC_RELAXED, __HIP_MEMORY_SCOPE_AGENT);
}
__device__ __forceinline__ void agent_store(float* p, float v) {
    __hip_atomic_store(p, v, __ATOMIC_RELAXED, __HIP_MEMORY_SCOPE_AGENT);
}
__device__ __forceinline__ unsigned flag_load(const unsigned* p) {
    return __hip_atomic_load(p, __ATOMIC_RELAXED, __HIP_MEMORY_SCOPE_AGENT);
}
__device__ __forceinline__ void flag_store(unsigned* p, unsigned v) {
    __hip_atomic_store(p, v, __ATOMIC_RELAXED, __HIP_MEMORY_SCOPE_AGENT);
}
__device__ __forceinline__ float agent_fadd(float* p, float v) {
    return __hip_atomic_fetch_add(p, v, __ATOMIC_RELAXED, __HIP_MEMORY_SCOPE_AGENT);
}

// Block barrier waiting ONLY on LDS ops (lgkmcnt): global prefetch loads
// stay in flight across it (__syncthreads would drain vmcnt(0)).
__device__ __forceinline__ void lds_barrier() {
    asm volatile("s_waitcnt lgkmcnt(0)\n\ts_barrier" ::: "memory");
}

// Hierarchical grid barrier; entry __syncthreads drains this block's
// data stores/atomics (vmcnt 0) before the arrival flag.
__device__ __forceinline__ void grid_barrier(int blk, unsigned base, unsigned phase) {
    const unsigned target = base + phase;
    __syncthreads();
    if (blk == 0) {
        if (threadIdx.x > 0 && threadIdx.x < 64) {
            for (;;) {
                unsigned f = flag_load(&g_arrive[threadIdx.x * 16]);
                if ((int)(f - target) >= 0) break;
                __builtin_amdgcn_s_sleep(1);
            }
        }
        if (threadIdx.x == 0) flag_store(&g_go, target);
    } else {
        if (threadIdx.x == 0) {
            flag_store(&g_arrive[blk * 16], target);
            for (;;) {
                unsigned f = flag_load(&g_go);
                if ((int)(f - target) >= 0) break;
                __builtin_amdgcn_s_sleep(1);
            }
        }
    }
    __syncthreads();
}

// Single launch, 64 blocks x 512 threads.
// GCN redundant per block; FC stages ROW-SPLIT (split-K) with device-scope
// atomicAdd — all weight loads are coalesced row reads (match row-major
// storage; each HBM line fetched once, fully used).
__global__ __launch_bounds__(512) void fused_kernel(
    const float* __restrict__ state,      // [B,21,128], only batch 0 used
    const int*   __restrict__ edge_index, // [2,128]
    const float* __restrict__ W1,         // [128,21]
    const float* __restrict__ b1,         // [21]
    const float* __restrict__ W2,         // [21,21]
    const float* __restrict__ b2,         // [21]
    const float* __restrict__ Wf1,        // [441,512]
    const float* __restrict__ bf1,        // [512]
    const float* __restrict__ Wf2,        // [512,512]
    const float* __restrict__ bf2,        // [512]
    const float* __restrict__ Wf3,        // [512,256]
    const float* __restrict__ bf3,        // [256]
    float* __restrict__ ws,
    float* __restrict__ out)
{
    const int b = blockIdx.x;
    const int t = threadIdx.x;

    const unsigned bbase = flag_load(&g_go);    // epoch bases (read at start,
    const unsigned cbase = flag_load(&g_cnt);   // before any advance)

    // ---------------- LDS ----------------
    __shared__ float sA[21 * APAD];
    __shared__ float sX[21 * W1PAD];
    __shared__ float sW1T[21 * W1PAD];
    __shared__ float sW2T[21 * APAD];
    __shared__ float sT[21 * APAD];      // h1T then h2T
    __shared__ float sG[21 * APAD];      // g1
    __shared__ float sv[441];
    __shared__ float sdeg[21];
    __shared__ float sb1[21], sb2[21];
    __shared__ float x1s[8], x2s[8];
    __shared__ unsigned sflag;

    // ---- P0: zero tiles, stage X/W1T/W2T, load edges, prefetch weights ----
    for (int i = t; i < 21 * APAD; i += 512) {
        sA[i] = 0.0f; sW2T[i] = 0.0f; sT[i] = 0.0f; sG[i] = 0.0f;
    }
    if (t < 21) { sdeg[t] = 1.0f; sb1[t] = b1[t]; sb2[t] = b2[t]; }
    {
        const float4* src4 = (const float4*)state;      // batch 0
        for (int i = t; i < 672; i += 512) {            // 21*128/4
            int n = i >> 5, fc = i & 31;
            ((float4*)&sX[n * W1PAD])[fc] = src4[i];
        }
    }
    for (int i = t; i < 2688; i += 512) {               // W1 -> sW1T[k][f]
        int f = i / 21, k = i - f * 21;
        sW1T[k * W1PAD + f] = W1[i];
    }
    for (int i = t; i < 441; i += 512) {                // W2 -> sW2T[k][f]
        int f = i / 21, k = i - f * 21;
        sW2T[k * APAD + f] = W2[i];
    }
    int er = 0, ec = 0;
    if (t < 128) { er = edge_index[t]; ec = edge_index[128 + t]; }

    // Coalesced row-prefetch of FC weights (block owns rows):
    float wf1v[7];
    if (b < 63) {
        #pragma unroll
        for (int i = 0; i < 7; ++i) wf1v[i] = Wf1[(size_t)(7 * b + i) * 512 + t];
    }
    float wf2v[8];
    #pragma unroll
    for (int i = 0; i < 8; ++i) wf2v[i] = Wf2[(size_t)(8 * b + i) * 512 + t];
    float wf3v[8];
    if (t < 256) {
        #pragma unroll
        for (int i = 0; i < 8; ++i) wf3v[i] = Wf3[(size_t)(8 * b + i) * 256 + t];
    }
    const float rbf1 = (t < 8) ? bf1[8 * b + t] : 0.0f;
    const float rbf2 = (t < 8) ? bf2[8 * b + t] : 0.0f;
    const float rbf3 = bf3[t & 255];

    // Block 0 zeroes the split-K accumulators (bypassing stores).
    if (b == 0) {
        agent_store(&ws[WS_ACC1 + t], 0.0f);
        agent_store(&ws[WS_ACC2 + t], 0.0f);
        if (t < 256) agent_store(&ws[WS_ACC3 + t], 0.0f);
    }

    // b1: block 0 uses __syncthreads (drains its zero stores); others lgkm-only.
    if (b == 0) __syncthreads(); else lds_barrier();
    if (b == 0 && t == 0) flag_store(&g_go, bbase + 1);   // zero-ready

    // ---- P1: adjacency scatter (+deg, +self-loop)  ||  h1 = X @ W1 ----
    if (t < 128) {
        atomicAdd(&sA[er * APAD + ec], 1.0f);
        atomicAdd(&sdeg[ec], 1.0f);
    }
    if (t < 21) atomicAdd(&sA[t * APAD + t], 1.0f);
    if (t < 441) {
        int n = t / 21, k = t - n * 21;
        const float4* x4 = (const float4*)&sX[n * W1PAD];
        const float4* w4 = (const float4*)&sW1T[k * W1PAD];
        float s = 0.0f;
        #pragma unroll
        for (int fc = 0; fc < 32; ++fc) {
            float4 a = x4[fc], ww = w4[fc];
            s += a.x * ww.x; s += a.y * ww.y; s += a.z * ww.z; s += a.w * ww.w;
        }
        sT[k * APAD + n] = s;
    }
    lds_barrier();

    // ---- P2: normalize A (dinv inlined; same expr/order as before) ----
    if (t < 441) {
        int r = t / 21, c = t - r * 21;
        float dr = 1.0f / sqrtf(sdeg[r]);
        float dc = 1.0f / sqrtf(sdeg[c]);
        sA[r * APAD + c] = dr * sA[r * APAD + c] * dc;
    }
    lds_barrier();

    // ---- P3: g1[i,k] = b1[k] + A[i,:] . h1T[k,:] ----
    if (t < 441) {
        int r = t / 21, k = t - r * 21;
        const float4* a4 = (const float4*)&sA[r * APAD];
        const float4* h4 = (const float4*)&sT[k * APAD];
        float s = sb1[k];
        #pragma unroll
        for (int jc = 0; jc < 6; ++jc) {
            float4 a = a4[jc], h = h4[jc];
            s += a.x * h.x; s += a.y * h.y; s += a.z * h.z; s += a.w * h.w;
        }
        sG[r * APAD + k] = s;
    }
    lds_barrier();

    // ---- P4: h2[n,k] = g1[n,:] . W2T[k,:] ----
    if (t < 441) {
        int n = t / 21, k = t - n * 21;
        const float4* g4 = (const float4*)&sG[n * APAD];
        const float4* w4 = (const float4*)&sW2T[k * APAD];
        float s = 0.0f;
        #pragma unroll
        for (int jc = 0; jc < 6; ++jc) {
            float4 g = g4[jc], ww = w4[jc];
            s += g.x * ww.x; s += g.y * ww.y; s += g.z * ww.z; s += g.w * ww.w;
        }
        sT[k * APAD + n] = s;
    }
    lds_barrier();

    // ---- P5: v[i*21+k] = b2[k] + A[i,:] . h2T[k,:] ----
    if (t < 441) {
        int r = t / 21, k = t - r * 21;
        const float4* a4 = (const float4*)&sA[r * APAD];
        const float4* h4 = (const float4*)&sT[k * APAD];
        float s = sb2[k];
        #pragma unroll
        for (int jc = 0; jc < 6; ++jc) {
            float4 a = a4[jc], h = h4[jc];
            s += a.x * h.x; s += a.y * h.y; s += a.z * h.z; s += a.w * h.w;
        }
        sv[t] = s;
    }
    lds_barrier();

    // ---- zero-ready gate (set long ago; ~one poll) ----
    if (t == 0) {
        while ((int)(flag_load(&g_go) - (bbase + 1)) < 0)
            __builtin_amdgcn_s_sleep(1);
    }
    __syncthreads();

    // ---- FC1 (row-split): block b rows [7b,7b+7), thread t = col ----
    if (b < 63) {
        float s = 0.0f;
        #pragma unroll
        for (int r = 0; r < 7; ++r) s += sv[7 * b + r] * wf1v[r];
        agent_fadd(&ws[WS_ACC1 + t], s);
    }

    grid_barrier(b, bbase, 2);

    // ---- FC2 (row-split): block b rows [8b,8b+8) ----
    if (t < 8) x1s[t] = fmaxf(agent_load(&ws[WS_ACC1 + 8 * b + t]) + rbf1, 0.0f);
    lds_barrier();
    {
        float s = 0.0f;
        #pragma unroll
        for (int j = 0; j < 8; ++j) s += x1s[j] * wf2v[j];
        agent_fadd(&ws[WS_ACC2 + t], s);
    }

    grid_barrier(b, bbase, 3);

    // ---- FC3 (row-split): block b rows [8b,8b+8), cols 0..255 ----
    if (t < 8) x2s[t] = fmaxf(agent_load(&ws[WS_ACC2 + 8 * b + t]) + rbf2, 0.0f);
    lds_barrier();
    if (t < 256) {
        float s = 0.0f;
        #pragma unroll
        for (int j = 0; j < 8; ++j) s += x2s[j] * wf3v[j];
        agent_fadd(&ws[WS_ACC3 + t], s);
    }

    // ---- finale: completion-count; the 64th block finalizes ----
    __syncthreads();                       // drain this block's FC3 adds
    if (t == 0) {
        unsigned prev = __hip_atomic_fetch_add(&g_cnt, 1u, __ATOMIC_RELAXED,
                                               __HIP_MEMORY_SCOPE_AGENT);
        sflag = (prev == cbase + 63u) ? 1u : 0u;
    }
    __syncthreads();
    if (sflag && t < 256) {
        float a = agent_load(&ws[WS_ACC3 + t]) + rbf3;
        out[t] = fmaxf(a, 0.0f);
    }
}

extern "C" void kernel_launch(void* const* d_in, const int* in_sizes, int n_in,
                              void* d_out, int out_size, void* d_ws, size_t ws_size,
                              hipStream_t stream)
{
    const float* state      = (const float*)d_in[0];
    const int*   edge_index = (const int*)  d_in[1];
    const float* W1  = (const float*)d_in[2];
    const float* b1  = (const float*)d_in[3];
    const float* W2  = (const float*)d_in[4];
    const float* b2  = (const float*)d_in[5];
    const float* Wf1 = (const float*)d_in[6];
    const float* bf1 = (const float*)d_in[7];
    const float* Wf2 = (const float*)d_in[8];
    const float* bf2 = (const float*)d_in[9];
    const float* Wf3 = (const float*)d_in[10];
    const float* bf3 = (const float*)d_in[11];

    float* ws  = (float*)d_ws;
    float* out = (float*)d_out;

    fused_kernel<<<64, 512, 0, stream>>>(state, edge_index, W1, b1, W2, b2,
                                         Wf1, bf1, Wf2, bf2, Wf3, bf3, ws, out);
}